// Round 2
// baseline (880.938 us; speedup 1.0000x reference)
//
#include <hip/hip_runtime.h>
#include <math.h>

typedef __bf16 bf16_t;
typedef __bf16 bfrag __attribute__((ext_vector_type(8)));
typedef float ffrag __attribute__((ext_vector_type(4)));

#define NBLK 256u

__device__ __forceinline__ float wave_sum(float v) {
#pragma unroll
  for (int m = 32; m >= 1; m >>= 1) v += __shfl_xor(v, m, 64);
  return v;
}
__device__ __forceinline__ float lin_(int i) { return -1.f + (2.f * (float)i) / 63.f; }
__device__ __forceinline__ float bflo(unsigned u) { return __uint_as_float(u << 16); }
__device__ __forceinline__ float bfhi(unsigned u) { return __uint_as_float(u & 0xFFFF0000u); }

// ---- software grid barrier: single-use counter per event, ws pre-zeroed ----
__device__ __forceinline__ void gbar(unsigned* ctr) {
  __syncthreads();
  if (threadIdx.x == 0) {
    __threadfence();                       // release: flush this XCD's L2
    atomicAdd(ctr, 1u);                    // device-scope arrive
    while (__hip_atomic_load(ctr, __ATOMIC_RELAXED, __HIP_MEMORY_SCOPE_AGENT) < NBLK)
      __builtin_amdgcn_s_sleep(1);
  }
  __syncthreads();
  __threadfence();                         // acquire: invalidate stale caches
}

struct FinS {
  float hsum_s[128], upd[64], sprev[64], xg[192], hg[192];
  float snew[64], xpre[64], hf[128], sfin[64], xn[64], qsh[64];
};
struct SmemPre {
  bf16_t xs[64][72];
  bf16_t t0s[64][72];
  bf16_t WTl[64][72];    // K weights then V weights (sequential passes)
  bf16_t W1l[128][72];
  float wpxs[64], wpys[64], bpvs[64];
};
struct SmemIter {
  float4 nckAl[128];
  float nckBl[128];
  float w2qTl[128][8];
  float4 scalV[64][9];
  float attnS[64][10];
  union { float HsumW[4][8][128]; FinS fin; };
  float momAcc[8][5];
};
struct Smem {
  unsigned P0kl[2][64 * 65];   // two tiles (batch b0, b0+4), persistent
  unsigned P0vl[2][64 * 65];
  float scr[2][640];           // per-tile LN stats hand-off (persistent)
  union { SmemPre pre; SmemIter it; } u;
};
static_assert(sizeof(Smem) == 118528, "layout");
static_assert(sizeof(Smem) <= 163840, "fits one block per CU");

// ---- one K-or-V projection pass: MFMA -> stats(regs) -> t0 -> P0 (LDS) ------
__device__ __forceinline__ void pass_type(
    const bf16_t (*xs)[72], bf16_t (*t0s)[72],
    const bf16_t (*WTl)[72], const bf16_t (*W1l)[72],
    const float* __restrict__ bias, const float* wpxs, const float* wpys,
    const float* bpvs, float st[5][4], unsigned* P0L,
    int wv, int lq, int ln15) {
  ffrag C[4] = {{0,0,0,0},{0,0,0,0},{0,0,0,0},{0,0,0,0}};
#pragma unroll
  for (int ks = 0; ks < 2; ++ks) {
    bfrag a = *(const bfrag*)&xs[wv * 16 + ln15][ks * 32 + lq * 8];
#pragma unroll
    for (int nt = 0; nt < 4; ++nt) {
      bfrag bb = *(const bfrag*)&WTl[nt * 16 + ln15][ks * 32 + lq * 8];
      C[nt] = __builtin_amdgcn_mfma_f32_16x16x32_bf16(a, bb, C[nt], 0, 0, 0);
    }
  }
  float kv[4][4];
#pragma unroll
  for (int i = 0; i < 5; ++i)
#pragma unroll
    for (int rg = 0; rg < 4; ++rg) st[i][rg] = 0.f;
#pragma unroll
  for (int nt = 0; nt < 4; ++nt) {
    int n = nt * 16 + ln15;
    float bn = bias[n], pxw = wpxs[n], pyw = wpys[n], bpw = bpvs[n];
#pragma unroll
    for (int rg = 0; rg < 4; ++rg) {
      float v = C[nt][rg] + bn;
      kv[nt][rg] = v;
      st[0][rg] += v; st[1][rg] += v * v; st[2][rg] += v * pxw;
      st[3][rg] += v * pyw; st[4][rg] += v * bpw;
    }
  }
#pragma unroll
  for (int i = 0; i < 5; ++i)
#pragma unroll
    for (int rg = 0; rg < 4; ++rg) {
      float v = st[i][rg];
      v += __shfl_xor(v, 1, 64); v += __shfl_xor(v, 2, 64);
      v += __shfl_xor(v, 4, 64); v += __shfl_xor(v, 8, 64);
      st[i][rg] = v;
    }
#pragma unroll
  for (int nt = 0; nt < 4; ++nt)
#pragma unroll
    for (int rg = 0; rg < 4; ++rg)
      t0s[wv * 16 + lq * 4 + rg][nt * 16 + ln15] = (bf16_t)kv[nt][rg];
  ffrag D[8] = {{0,0,0,0},{0,0,0,0},{0,0,0,0},{0,0,0,0},
                {0,0,0,0},{0,0,0,0},{0,0,0,0},{0,0,0,0}};
#pragma unroll
  for (int ks = 0; ks < 2; ++ks) {
    bfrag a = *(const bfrag*)&t0s[wv * 16 + ln15][ks * 32 + lq * 8];
#pragma unroll
    for (int nt = 0; nt < 8; ++nt) {
      bfrag bb = *(const bfrag*)&W1l[nt * 16 + ln15][ks * 32 + lq * 8];
      D[nt] = __builtin_amdgcn_mfma_f32_16x16x32_bf16(a, bb, D[nt], 0, 0, 0);
    }
  }
  bf16_t* P16 = (bf16_t*)P0L;
#pragma unroll
  for (int nt = 0; nt < 8; ++nt)
#pragma unroll
    for (int rg = 0; rg < 4; ++rg)
      P16[(wv * 16 + lq * 4 + rg) * 130 + nt * 16 + ln15] = (bf16_t)D[nt][rg];
}

// ============ single persistent kernel: 256 blocks, 2 tiles each =============
__global__ __launch_bounds__(256) void k_fused(
    const float* __restrict__ inp,       // in[0]
    const float* __restrict__ slots_p,   // 1
    const float* __restrict__ s_pos_p,   // 2
    const float* __restrict__ s_scale_p, // 3
    const float* __restrict__ W_pos,     // 4
    const float* __restrict__ b_pos,     // 5
    const float* __restrict__ Wq,        // 6
    const float* __restrict__ bq,        // 7
    const float* __restrict__ Wk,        // 8
    const float* __restrict__ bk,        // 9
    const float* __restrict__ Wv,        // 10
    const float* __restrict__ bv,        // 11
    const float* __restrict__ g_in,      // 12
    const float* __restrict__ b_in,      // 13
    const float* __restrict__ g_slots,   // 14
    const float* __restrict__ b_slots,   // 15
    const float* __restrict__ g_k,       // 16
    const float* __restrict__ b_k,       // 17
    const float* __restrict__ g_v,       // 18
    const float* __restrict__ b_v,       // 19
    const float* __restrict__ W1,        // 20
    const float* __restrict__ b1,        // 21
    const float* __restrict__ W2,        // 22
    const float* __restrict__ b2,        // 23
    const float* __restrict__ W_ih,      // 24
    const float* __restrict__ b_ih,      // 25
    const float* __restrict__ W_hh,      // 26
    const float* __restrict__ b_hh,      // 27
    const float* __restrict__ g_pre,     // 28
    const float* __restrict__ b_pre,     // 29
    const float* __restrict__ Wf1,       // 30
    const float* __restrict__ bf1,       // 31
    const float* __restrict__ Wf2,       // 32
    const float* __restrict__ bf2,       // 33
    float* __restrict__ ws,
    float* __restrict__ outSlots, float* __restrict__ outSpos,
    float* __restrict__ outSscale, float* __restrict__ outAttn) {
  __shared__ Smem sm;
  const int tid = threadIdx.x;
  const int bid = blockIdx.x;
  const int tl = bid & 63;       // spatial tile (same for both owned batches)
  const int b0 = bid >> 6;       // batch of tile 0; tile 1 is batch b0+4

  // workspace layout (floats)
  float* slotsS  = ws;            // 4096
  float* sposS   = ws + 4096;     // 128
  float* sscaleS = ws + 4224;     // 128
  float* moments = ws + 4352;     // 320   (contiguous with Hsum: 8512)
  float* Hsum    = ws + 4672;     // 8192
  float* w2qg    = ws + 12864;    // 8192
  float* b2qg    = ws + 21056;    // 64
  bf16_t* W1kT   = (bf16_t*)(ws + 21120);  // 8192 bf16
  bf16_t* W1vT   = (bf16_t*)(ws + 25216);
  bf16_t* WkT    = (bf16_t*)(ws + 29312);  // 4096 bf16
  bf16_t* WvT    = (bf16_t*)(ws + 31360);
  float4* nckA   = (float4*)(ws + 33408);  // 128 float4
  float* nckB    = ws + 33920;             // 128
  float4* ncvA   = (float4*)(ws + 34048);
  float* ncvB    = ws + 34560;
  float* possum  = ws + 34688;             // 9
  unsigned* bar  = (unsigned*)(ws + 34816); // 9 events x 16 uints (zeroed by host memset)

  // ---- setup (block 0 only): state init + folded-weight precompute ----------
  if (bid == 0) {
    int t = tid;
    for (int i = t; i < 8512; i += 256) moments[i] = 0.f;  // moments+Hsum
    for (int i = t; i < 4096; i += 256) slotsS[i] = slots_p[i & 511];
    if (t < 128) {
      sposS[t] = fminf(fmaxf(s_pos_p[t & 15], -1.f), 1.f);
      sscaleS[t] = fminf(fmaxf(s_scale_p[t & 15], 0.001f), 2.f);
    }
    for (int i = t; i < 4096; i += 256) {
      int n = i >> 6, d = i & 63;
      WkT[i] = (bf16_t)Wk[d * 64 + n];
      WvT[i] = (bf16_t)Wv[d * 64 + n];
    }
    if (t < 128) {
      int n = t;
      float wxk = 0, wyk = 0, wbk = 0, uk = 0, sk = 0;
      float wxv = 0, wyv = 0, wbv = 0, uv = 0, sv = 0;
      for (int c = 0; c < 64; ++c) {
        float w = W1[c * 128 + n];
        float wkk = g_k[c] * w, wvv = g_v[c] * w;
        W1kT[n * 64 + c] = (bf16_t)wkk;
        W1vT[n * 64 + c] = (bf16_t)wvv;
        float pxc = W_pos[c], pyc = W_pos[64 + c], bpc = b_pos[c];
        wxk += pxc * wkk; wyk += pyc * wkk; wbk += bpc * wkk; sk += wkk; uk += b_k[c] * w;
        wxv += pxc * wvv; wyv += pyc * wvv; wbv += bpc * wvv; sv += wvv; uv += b_v[c] * w;
      }
      nckA[n] = make_float4(wxk, wyk, wbk, uk + b1[n]); nckB[n] = sk;
      ncvA[n] = make_float4(wxv, wyv, wbv, uv + b1[n]); ncvB[n] = sv;
    }
    if (t < 64) {
      float pxc = W_pos[t], pyc = W_pos[64 + t], bpc = b_pos[t];
      float s9[9] = {pxc, pyc, bpc, pxc * pxc, pyc * pyc, bpc * bpc,
                     pxc * pyc, pxc * bpc, pyc * bpc};
#pragma unroll
      for (int i = 0; i < 9; ++i) {
        float v = wave_sum(s9[i]);
        if (t == 0) possum[i] = v;
      }
    }
  }
  gbar(&bar[0]);  // event 0: setup visible everywhere

  // ---- pre phase: per owned tile, LN(inp) -> K pass -> V pass ---------------
  const int wv = tid >> 6, lane = tid & 63, lq = lane >> 4, ln15 = lane & 15;
  for (int u = 0; u < 2; ++u) {
    const int j0 = (bid + u * 256) * 64;
    {
      const int pxl = tid >> 2, cgl = tid & 3;
      const float* rowp = inp + (size_t)(j0 + pxl) * 64 + cgl * 16;
      float v[16];
      *(float4*)&v[0]  = ((const float4*)rowp)[0];
      *(float4*)&v[4]  = ((const float4*)rowp)[1];
      *(float4*)&v[8]  = ((const float4*)rowp)[2];
      *(float4*)&v[12] = ((const float4*)rowp)[3];
      float s = 0.f, s2 = 0.f;
#pragma unroll
      for (int i = 0; i < 16; ++i) { s += v[i]; s2 += v[i] * v[i]; }
      s += __shfl_xor(s, 1, 64); s += __shfl_xor(s, 2, 64);
      s2 += __shfl_xor(s2, 1, 64); s2 += __shfl_xor(s2, 2, 64);
      float m = s * 0.015625f;
      float r = rsqrtf(s2 * 0.015625f - m * m + 1e-5f);
      float g[16], bb[16];
      *(float4*)&g[0]  = ((const float4*)(g_in + cgl * 16))[0];
      *(float4*)&g[4]  = ((const float4*)(g_in + cgl * 16))[1];
      *(float4*)&g[8]  = ((const float4*)(g_in + cgl * 16))[2];
      *(float4*)&g[12] = ((const float4*)(g_in + cgl * 16))[3];
      *(float4*)&bb[0]  = ((const float4*)(b_in + cgl * 16))[0];
      *(float4*)&bb[4]  = ((const float4*)(b_in + cgl * 16))[1];
      *(float4*)&bb[8]  = ((const float4*)(b_in + cgl * 16))[2];
      *(float4*)&bb[12] = ((const float4*)(b_in + cgl * 16))[3];
#pragma unroll
      for (int e = 0; e < 8; ++e) {
        float x0 = (v[2 * e] - m) * r * g[2 * e] + bb[2 * e];
        float x1 = (v[2 * e + 1] - m) * r * g[2 * e + 1] + bb[2 * e + 1];
        union { unsigned uu; bf16_t h[2]; } cv;
        cv.h[0] = (bf16_t)x0; cv.h[1] = (bf16_t)x1;
        *(unsigned*)&sm.u.pre.xs[pxl][cgl * 16 + 2 * e] = cv.uu;
      }
    }
    if (u == 0 && tid < 64) {
      sm.u.pre.wpxs[tid] = W_pos[tid];
      sm.u.pre.wpys[tid] = W_pos[64 + tid];
      sm.u.pre.bpvs[tid] = b_pos[tid];
    }
    for (int i = tid; i < 512; i += 256) {
      int row = i >> 3, seg = i & 7;
      *(uint4*)&sm.u.pre.WTl[row][seg * 8] = ((const uint4*)WkT)[i];
    }
    for (int i = tid; i < 1024; i += 256) {
      int row = i >> 3, seg = i & 7;
      *(uint4*)&sm.u.pre.W1l[row][seg * 8] = ((const uint4*)W1kT)[i];
    }
    __syncthreads();
    float stK[5][4], stV[5][4];
    pass_type(sm.u.pre.xs, sm.u.pre.t0s, sm.u.pre.WTl, sm.u.pre.W1l, bk,
              sm.u.pre.wpxs, sm.u.pre.wpys, sm.u.pre.bpvs, stK, sm.P0kl[u],
              wv, lq, ln15);
    __syncthreads();
    for (int i = tid; i < 512; i += 256) {
      int row = i >> 3, seg = i & 7;
      *(uint4*)&sm.u.pre.WTl[row][seg * 8] = ((const uint4*)WvT)[i];
    }
    for (int i = tid; i < 1024; i += 256) {
      int row = i >> 3, seg = i & 7;
      *(uint4*)&sm.u.pre.W1l[row][seg * 8] = ((const uint4*)W1vT)[i];
    }
    __syncthreads();
    pass_type(sm.u.pre.xs, sm.u.pre.t0s, sm.u.pre.WTl, sm.u.pre.W1l, bv,
              sm.u.pre.wpxs, sm.u.pre.wpys, sm.u.pre.bpvs, stV, sm.P0vl[u],
              wv, lq, ln15);
    if (ln15 == 0) {
#pragma unroll
      for (int rg = 0; rg < 4; ++rg) {
        int row = wv * 16 + lq * 4 + rg;
#pragma unroll
        for (int i = 0; i < 5; ++i) {
          sm.scr[u][row * 5 + i] = stK[i][rg];
          sm.scr[u][320 + row * 5 + i] = stV[i][rg];
        }
      }
    }
    __syncthreads();  // frees xs/t0s/WTl for next tile; orders scr writes
  }

  // stage loop-invariant iter tables (overwrites pre region)
  if (tid < 128) { sm.u.it.nckAl[tid] = nckA[tid]; sm.u.it.nckBl[tid] = nckB[tid]; }
  float4 ncv0, ncv1; float wsv0, wsv1;
  { int l = tid & 63; ncv0 = ncvA[l]; ncv1 = ncvA[l + 64]; wsv0 = ncvB[l]; wsv1 = ncvB[l + 64]; }
  const float Swx = possum[0], Swy = possum[1], Sbp = possum[2];
  const float Swx2 = possum[3], Swy2 = possum[4], Sbp2 = possum[5];
  const float Swxy = possum[6], Swxb = possum[7], Swyb = possum[8];
  const int px = tid >> 2, sp = tid & 3;
  const int jimg = tl * 64 + px;
  const float gx = lin_(px), gy = lin_(tl);

  // initial q / w2q / b2q (first 64 blocks; register/global only)
  if (bid < 64 && tid < 64) {
    int bs = bid, d = tid;
    float v = slotsS[bs * 64 + d];
    float m = wave_sum(v) * 0.015625f;
    float c = v - m;
    float var = wave_sum(c * c) * 0.015625f;
    float xnv = c * rsqrtf(var + 1e-5f) * g_slots[d] + b_slots[d];
    float q = bq[d];
    for (int cc = 0; cc < 64; ++cc) q = fmaf(__shfl(xnv, cc, 64), Wq[cc * 64 + d], q);
    float w0 = 0.f, w1 = 0.f;
    for (int cc = 0; cc < 64; ++cc) {
      float qc = __shfl(q, cc, 64);
      w0 = fmaf(W2[d * 64 + cc], qc, w0);
      w1 = fmaf(W2[(64 + d) * 64 + cc], qc, w1);
    }
    w2qg[bs * 128 + d] = w0;
    w2qg[bs * 128 + 64 + d] = w1;
    float p = wave_sum(b2[d] * q);
    if (d == 0) b2qg[bs] = p;
  }

  // ---- 4 slot-attention iterations ------------------------------------------
  for (int itn = 0; itn < 4; ++itn) {
    const int last = (itn == 3);
    gbar(&bar[(1 + 2 * itn) * 16]);  // iteration inputs ready

#pragma unroll
    for (int u = 0; u < 2; ++u) {
      const int b_u = b0 + 4 * u;
#pragma unroll
      for (int r = 0; r < 4; ++r) {
        int idx = tid + 256 * r;
        int s = idx >> 7, n = idx & 127;
        sm.u.it.w2qTl[n][s] = w2qg[(b_u * 8 + s) * 128 + n];
      }
      if (tid < 40) sm.u.it.momAcc[tid / 5][tid % 5] = 0.f;
      __syncthreads();

      // -- phase 1: dots for 8 slots, softmax, spatial moments
      float skA[5], svA[5];
#pragma unroll
      for (int i = 0; i < 5; ++i) {
        skA[i] = sm.scr[u][px * 5 + i];
        svA[i] = sm.scr[u][320 + px * 5 + i];
      }
      float c1a[8], c2a[8], rKa[8], mrKa[8];
#pragma unroll
      for (int s = 0; s < 8; ++s) {
        int bs = b_u * 8 + s;
        float spx = sposS[bs * 2], spy = sposS[bs * 2 + 1];
        float rxx = 1.f / (sscaleS[bs * 2] * 5.f);
        float ryy = 1.f / (sscaleS[bs * 2 + 1] * 5.f);
        float c1 = (gx - spx) * rxx, c2 = (gy - spy) * ryy;
        float quad = c1 * c1 * Swx2 + c2 * c2 * Swy2 + Sbp2 +
                     2.f * (c1 * c2 * Swxy + c1 * Swxb + c2 * Swyb);
        float mK = (skA[0] + c1 * Swx + c2 * Swy + Sbp) * 0.015625f;
        float e2K = (skA[1] + 2.f * (c1 * skA[2] + c2 * skA[3] + skA[4]) + quad) * 0.015625f;
        float rK = rsqrtf(e2K - mK * mK + 1e-5f);
        c1a[s] = c1; c2a[s] = c2; rKa[s] = rK; mrKa[s] = mK * rK;
        if (!last && (s >> 1) == sp) {
          float mV = (svA[0] + c1 * Swx + c2 * Swy + Sbp) * 0.015625f;
          float e2V = (svA[1] + 2.f * (c1 * svA[2] + c2 * svA[3] + svA[4]) + quad) * 0.015625f;
          float rV = rsqrtf(e2V - mV * mV + 1e-5f);
          sm.u.it.scalV[px][s] = make_float4(c1, c2, rV, mV * rV);
        }
      }
      float d8[8] = {0, 0, 0, 0, 0, 0, 0, 0};
#pragma unroll 4
      for (int i = 0; i < 16; ++i) {
        int k = sp * 16 + i;
        unsigned uu = sm.P0kl[u][px * 65 + k];
        float p0 = bflo(uu), p1 = bfhi(uu);
        float4 A0 = sm.u.it.nckAl[2 * k], A1 = sm.u.it.nckAl[2 * k + 1];
        float ws0 = sm.u.it.nckBl[2 * k], ws1 = sm.u.it.nckBl[2 * k + 1];
        float4 q0a = *(const float4*)&sm.u.it.w2qTl[2 * k][0];
        float4 q0b = *(const float4*)&sm.u.it.w2qTl[2 * k][4];
        float4 q1a = *(const float4*)&sm.u.it.w2qTl[2 * k + 1][0];
        float4 q1b = *(const float4*)&sm.u.it.w2qTl[2 * k + 1][4];
        float qq0[8] = {q0a.x, q0a.y, q0a.z, q0a.w, q0b.x, q0b.y, q0b.z, q0b.w};
        float qq1[8] = {q1a.x, q1a.y, q1a.z, q1a.w, q1b.x, q1b.y, q1b.z, q1b.w};
        float bm0 = p0 + A0.z, bm1 = p1 + A1.z;
#pragma unroll
        for (int s = 0; s < 8; ++s) {
          float z0 = bm0 + c1a[s] * A0.x + c2a[s] * A0.y;
          float h0 = fmaxf(fmaf(rKa[s], z0, fmaf(-mrKa[s], ws0, A0.w)), 0.f);
          d8[s] = fmaf(h0, qq0[s], d8[s]);
          float z1 = bm1 + c1a[s] * A1.x + c2a[s] * A1.y;
          float h1 = fmaxf(fmaf(rKa[s], z1, fmaf(-mrKa[s], ws1, A1.w)), 0.f);
          d8[s] = fmaf(h1, qq1[s], d8[s]);
        }
      }
#pragma unroll
      for (int s = 0; s < 8; ++s) {
        float v = d8[s];
        v += __shfl_xor(v, 1, 64);
        v += __shfl_xor(v, 2, 64);
        d8[s] = (v + b2qg[b_u * 8 + s]) * 0.125f;
      }
      float mx = d8[0];
#pragma unroll
      for (int s = 1; s < 8; ++s) mx = fmaxf(mx, d8[s]);
      float tt = 0.f;
      float e8[8];
#pragma unroll
      for (int s = 0; s < 8; ++s) { e8[s] = expf(d8[s] - mx); tt += e8[s]; }
      float inv = 1.f / tt;
#pragma unroll
      for (int s = 0; s < 8; ++s) e8[s] = e8[s] * inv + 1e-8f;
      float wa, wb;
      if (sp == 0) { wa = e8[0]; wb = e8[1]; }
      else if (sp == 1) { wa = e8[2]; wb = e8[3]; }
      else if (sp == 2) { wa = e8[4]; wb = e8[5]; }
      else { wa = e8[6]; wb = e8[7]; }
      *(float2*)&sm.u.it.attnS[px][sp * 2] = make_float2(wa, wb);
      if (last) {
        outAttn[(size_t)(b_u * 8 + sp * 2) * 4096 + jimg] = wa;
        outAttn[(size_t)(b_u * 8 + sp * 2 + 1) * 4096 + jimg] = wb;
      }
      {
        float mm[10] = {wa, wa * gx, wa * gy, wa * gx * gx, wa * gy * gy,
                        wb, wb * gx, wb * gy, wb * gx * gx, wb * gy * gy};
#pragma unroll
        for (int i = 0; i < 10; ++i) {
          float v = mm[i];
          v += __shfl_xor(v, 4, 64); v += __shfl_xor(v, 8, 64);
          v += __shfl_xor(v, 16, 64); v += __shfl_xor(v, 32, 64);
          mm[i] = v;
        }
        if ((tid & 63) < 4) {
#pragma unroll
          for (int i = 0; i < 5; ++i) {
            atomicAdd(&sm.u.it.momAcc[sp * 2][i], mm[i]);
            atomicAdd(&sm.u.it.momAcc[sp * 2 + 1][i], mm[5 + i]);
          }
        }
      }
      __syncthreads();

      // -- phase 2: Hsum += attn * relu(V hidden)
      if (!last) {
        const int w = tid >> 6, l = tid & 63;
        float hacc[8][2];
#pragma unroll
        for (int s = 0; s < 8; ++s) { hacc[s][0] = 0.f; hacc[s][1] = 0.f; }
        const unsigned short* P16 = (const unsigned short*)sm.P0vl[u];
#pragma unroll 2
        for (int i = 0; i < 16; ++i) {
          int j = w * 16 + i;
          float pv0 = __uint_as_float((unsigned)P16[j * 130 + l] << 16);
          float pv1 = __uint_as_float((unsigned)P16[j * 130 + 64 + l] << 16);
          float bm0 = pv0 + ncv0.z, bm1 = pv1 + ncv1.z;
#pragma unroll
          for (int s = 0; s < 8; ++s) {
            float4 sc = sm.u.it.scalV[j][s];
            float aw = sm.u.it.attnS[j][s];
            float z0 = bm0 + sc.x * ncv0.x + sc.y * ncv0.y;
            float h0 = fmaxf(fmaf(sc.z, z0, fmaf(-sc.w, wsv0, ncv0.w)), 0.f);
            hacc[s][0] = fmaf(aw, h0, hacc[s][0]);
            float z1 = bm1 + sc.x * ncv1.x + sc.y * ncv1.y;
            float h1 = fmaxf(fmaf(sc.z, z1, fmaf(-sc.w, wsv1, ncv1.w)), 0.f);
            hacc[s][1] = fmaf(aw, h1, hacc[s][1]);
          }
        }
#pragma unroll
        for (int s = 0; s < 8; ++s) {
          sm.u.it.HsumW[w][s][l] = hacc[s][0];
          sm.u.it.HsumW[w][s][l + 64] = hacc[s][1];
        }
        __syncthreads();
#pragma unroll
        for (int r = 0; r < 4; ++r) {
          int i = tid + 256 * r;
          int s = i >> 7, n = i & 127;
          float v = sm.u.it.HsumW[0][s][n] + sm.u.it.HsumW[1][s][n] +
                    sm.u.it.HsumW[2][s][n] + sm.u.it.HsumW[3][s][n];
          atomicAdd(&Hsum[(b_u * 8 + s) * 128 + n], v);
        }
      }
      if (tid < 40)
        atomicAdd(&moments[(b_u * 8 + tid / 5) * 5 + tid % 5],
                  sm.u.it.momAcc[tid / 5][tid % 5]);
      __syncthreads();  // protect w2qTl/momAcc/HsumW before next tile
    }

    gbar(&bar[(2 + 2 * itn) * 16]);  // all moments/Hsum contributions complete

    // -- finalize (64 blocks, one per (b,s)): sp/ss, GRU+FFN, next-iter q -----
    if (bid < 64) {
      const int bs = bid;
      const int t = tid;
      FinS& F = sm.u.it.fin;
      const float M0 = moments[bs * 5 + 0];
      const float M1x = moments[bs * 5 + 1], M1y = moments[bs * 5 + 2];
      const float M2x = moments[bs * 5 + 3], M2y = moments[bs * 5 + 4];
      const float invM0 = 1.f / M0;
      const float spx = M1x * invM0, spy = M1y * invM0;
      const float M0a = M0 + 4096.f * 1e-8f;
      const float G2 = 1408.6772487f * 1e-8f;
      const float vx = (M2x + G2 - 2.f * spx * M1x + spx * spx * M0a) / M0a;
      const float vy = (M2y + G2 - 2.f * spy * M1y + spy * spy * M0a) / M0a;
      float ssx = sqrtf(fmaxf(vx, 0.f)), ssy = sqrtf(fmaxf(vy, 0.f));
      ssx = fminf(fmaxf(ssx, 0.001f), 2.f);
      ssy = fminf(fmaxf(ssy, 0.001f), 2.f);
      if (t == 0) {
        sposS[bs * 2 + 0] = spx; sposS[bs * 2 + 1] = spy;
        sscaleS[bs * 2 + 0] = ssx; sscaleS[bs * 2 + 1] = ssy;
        if (last) {
          outSpos[bs * 2 + 0] = spx; outSpos[bs * 2 + 1] = spy;
          outSscale[bs * 2 + 0] = ssx; outSscale[bs * 2 + 1] = ssy;
        }
      }
      if (last) {
        if (t < 64) outSlots[bs * 64 + t] = slotsS[bs * 64 + t];
      } else {
        if (t < 128) F.hsum_s[t] = Hsum[bs * 128 + t];
        if (t < 64) F.sprev[t] = slotsS[bs * 64 + t];
        __syncthreads();
        if (t < 128) Hsum[bs * 128 + t] = 0.f;
        if (t < 5) moments[bs * 5 + t] = 0.f;
        if (t < 64) {
          float a = 0.f;
#pragma unroll
          for (int k = 0; k < 128; ++k) a += F.hsum_s[k] * W2[k * 64 + t];
          F.upd[t] = a * invM0 + b2[t];
        }
        __syncthreads();
        if (t < 192) {
          float a = b_ih[t], h = b_hh[t];
#pragma unroll
          for (int d = 0; d < 64; ++d) {
            a += F.upd[d] * W_ih[d * 192 + t];
            h += F.sprev[d] * W_hh[d * 192 + t];
          }
          F.xg[t] = a; F.hg[t] = h;
        }
        __syncthreads();
        if (t < 64) {
          float r = 1.f / (1.f + expf(-(F.xg[t] + F.hg[t])));
          float z = 1.f / (1.f + expf(-(F.xg[64 + t] + F.hg[64 + t])));
          float n = tanhf(F.xg[128 + t] + r * F.hg[128 + t]);
          F.snew[t] = (1.f - z) * n + z * F.sprev[t];
        }
        __syncthreads();
        if (t < 64) {
          float v = F.snew[t];
          float m = wave_sum(v) * 0.015625f;
          float c = v - m;
          float var = wave_sum(c * c) * 0.015625f;
          F.xpre[t] = c * rsqrtf(var + 1e-5f) * g_pre[t] + b_pre[t];
        }
        __syncthreads();
        if (t < 128) {
          float a = bf1[t];
#pragma unroll
          for (int d = 0; d < 64; ++d) a += F.xpre[d] * Wf1[d * 128 + t];
          F.hf[t] = fmaxf(a, 0.f);
        }
        __syncthreads();
        if (t < 64) {
          float a = bf2[t];
#pragma unroll
          for (int k = 0; k < 128; ++k) a += F.hf[k] * Wf2[k * 64 + t];
          float nv = F.snew[t] + a;
          slotsS[bs * 64 + t] = nv;
          F.sfin[t] = nv;
        }
        __syncthreads();
        if (t < 64) {
          float v = F.sfin[t];
          float m = wave_sum(v) * 0.015625f;
          float c = v - m;
          float var = wave_sum(c * c) * 0.015625f;
          F.xn[t] = c * rsqrtf(var + 1e-5f) * g_slots[t] + b_slots[t];
        }
        __syncthreads();
        if (t < 64) {
          float a = bq[t];
#pragma unroll
          for (int d = 0; d < 64; ++d) a += F.xn[d] * Wq[d * 64 + t];
          F.qsh[t] = a;
        }
        __syncthreads();
        if (t < 128) {
          float a = 0.f;
#pragma unroll
          for (int d = 0; d < 64; ++d) a += W2[t * 64 + d] * F.qsh[d];
          w2qg[bs * 128 + t] = a;
        }
        if (t < 64) {
          float p = wave_sum(b2[t] * F.qsh[t]);
          if (t == 0) b2qg[bs] = p;
        }
      }
    }
  }
}

extern "C" void kernel_launch(void* const* d_in, const int* in_sizes, int n_in,
                              void* d_out, int out_size, void* d_ws, size_t ws_size,
                              hipStream_t stream) {
  (void)in_sizes; (void)n_in; (void)out_size; (void)ws_size;
  const float* const* in = (const float* const*)d_in;
  float* wsp = (float*)d_ws;
  float* out = (float*)d_out;
  float* oSlots = out;
  float* oSpos = out + 4096;
  float* oSscale = out + 4224;
  float* oAttn = out + 4352;

  // zero the 9 grid-barrier counters (ws float offset 34816 = byte 139264)
  hipMemsetAsync((char*)d_ws + 139264, 0, 576, stream);

  k_fused<<<NBLK, 256, 0, stream>>>(
      in[0], in[1], in[2], in[3], in[4], in[5], in[6], in[7], in[8], in[9],
      in[10], in[11], in[12], in[13], in[14], in[15], in[16], in[17], in[18],
      in[19], in[20], in[21], in[22], in[23], in[24], in[25], in[26], in[27],
      in[28], in[29], in[30], in[31], in[32], in[33],
      wsp, oSlots, oSpos, oSscale, oAttn);
}

// Round 3
// 287.093 us; speedup vs baseline: 3.0685x; 3.0685x over previous
//
#include <hip/hip_runtime.h>
#include <math.h>

typedef __bf16 bf16_t;
typedef __bf16 bfrag __attribute__((ext_vector_type(8)));
typedef float ffrag __attribute__((ext_vector_type(4)));

__device__ __forceinline__ float wave_sum(float v) {
#pragma unroll
  for (int m = 32; m >= 1; m >>= 1) v += __shfl_xor(v, m, 64);
  return v;
}
__device__ __forceinline__ float lin_(int i) { return -1.f + (2.f * (float)i) / 63.f; }
__device__ __forceinline__ float bflo(unsigned u) { return __uint_as_float(u << 16); }
__device__ __forceinline__ float bfhi(unsigned u) { return __uint_as_float(u & 0xFFFF0000u); }

// ============ k_pre: LN(inp) -> K/V hidden P0 + LN stats; self-folds weights =
__device__ __forceinline__ void pass_type(
    const bf16_t xs[][72], bf16_t t0s[][72],
    const bf16_t WTl[][72], const bf16_t W1l[][72],
    const float* __restrict__ bias, const float* wpxs, const float* wpys,
    const float* bpvs, float* __restrict__ statsG, bf16_t* __restrict__ P0G,
    int j0, int wv, int lq, int ln15) {
  ffrag C[4] = {{0,0,0,0},{0,0,0,0},{0,0,0,0},{0,0,0,0}};
#pragma unroll
  for (int ks = 0; ks < 2; ++ks) {
    bfrag a = *(const bfrag*)&xs[wv * 16 + ln15][ks * 32 + lq * 8];
#pragma unroll
    for (int nt = 0; nt < 4; ++nt) {
      bfrag bb = *(const bfrag*)&WTl[nt * 16 + ln15][ks * 32 + lq * 8];
      C[nt] = __builtin_amdgcn_mfma_f32_16x16x32_bf16(a, bb, C[nt], 0, 0, 0);
    }
  }
  float kv[4][4];
  float st[5][4];
#pragma unroll
  for (int i = 0; i < 5; ++i)
#pragma unroll
    for (int rg = 0; rg < 4; ++rg) st[i][rg] = 0.f;
#pragma unroll
  for (int nt = 0; nt < 4; ++nt) {
    int n = nt * 16 + ln15;
    float bn = bias[n], pxw = wpxs[n], pyw = wpys[n], bpw = bpvs[n];
#pragma unroll
    for (int rg = 0; rg < 4; ++rg) {
      float v = C[nt][rg] + bn;
      kv[nt][rg] = v;
      st[0][rg] += v; st[1][rg] += v * v; st[2][rg] += v * pxw;
      st[3][rg] += v * pyw; st[4][rg] += v * bpw;
    }
  }
#pragma unroll
  for (int i = 0; i < 5; ++i)
#pragma unroll
    for (int rg = 0; rg < 4; ++rg) {
      float v = st[i][rg];
      v += __shfl_xor(v, 1, 64); v += __shfl_xor(v, 2, 64);
      v += __shfl_xor(v, 4, 64); v += __shfl_xor(v, 8, 64);
      st[i][rg] = v;
    }
  if (ln15 == 0) {
#pragma unroll
    for (int rg = 0; rg < 4; ++rg) {
      int j = j0 + wv * 16 + lq * 4 + rg;
#pragma unroll
      for (int i = 0; i < 5; ++i) statsG[j * 5 + i] = st[i][rg];
    }
  }
#pragma unroll
  for (int nt = 0; nt < 4; ++nt)
#pragma unroll
    for (int rg = 0; rg < 4; ++rg)
      t0s[wv * 16 + lq * 4 + rg][nt * 16 + ln15] = (bf16_t)kv[nt][rg];
  ffrag D[8] = {{0,0,0,0},{0,0,0,0},{0,0,0,0},{0,0,0,0},
                {0,0,0,0},{0,0,0,0},{0,0,0,0},{0,0,0,0}};
#pragma unroll
  for (int ks = 0; ks < 2; ++ks) {
    bfrag a = *(const bfrag*)&t0s[wv * 16 + ln15][ks * 32 + lq * 8];
#pragma unroll
    for (int nt = 0; nt < 8; ++nt) {
      bfrag bb = *(const bfrag*)&W1l[nt * 16 + ln15][ks * 32 + lq * 8];
      D[nt] = __builtin_amdgcn_mfma_f32_16x16x32_bf16(a, bb, D[nt], 0, 0, 0);
    }
  }
#pragma unroll
  for (int nt = 0; nt < 8; ++nt)
#pragma unroll
    for (int rg = 0; rg < 4; ++rg)
      P0G[(size_t)(j0 + wv * 16 + lq * 4 + rg) * 128 + nt * 16 + ln15] =
          (bf16_t)D[nt][rg];
}

__global__ __launch_bounds__(256) void k_pre(
    const float* __restrict__ inp, const float* __restrict__ g_in,
    const float* __restrict__ b_in, const float* __restrict__ bk,
    const float* __restrict__ bv, const float* __restrict__ Wk,
    const float* __restrict__ Wv, const float* __restrict__ W1,
    const float* __restrict__ g_k, const float* __restrict__ g_v,
    const float* __restrict__ W_pos, const float* __restrict__ b_pos,
    bf16_t* __restrict__ P0k, bf16_t* __restrict__ P0v,
    float* __restrict__ statsK, float* __restrict__ statsV,
    const float* __restrict__ slots_p, const float* __restrict__ g_slots,
    const float* __restrict__ b_slots, const float* __restrict__ Wq,
    const float* __restrict__ bq, const float* __restrict__ W2,
    const float* __restrict__ b2, float* __restrict__ w2qg,
    float* __restrict__ b2qg,
    const float* __restrict__ b_k, const float* __restrict__ b_v,
    const float* __restrict__ b1, const float* __restrict__ s_pos_p,
    const float* __restrict__ s_scale_p,
    float4* __restrict__ nckA, float* __restrict__ nckB,
    float4* __restrict__ ncvA, float* __restrict__ ncvB,
    float* __restrict__ possum, float* __restrict__ sposS,
    float* __restrict__ sscaleS, float* __restrict__ slotsS) {
  __shared__ bf16_t xs[64][72];
  __shared__ bf16_t t0s[64][72];
  __shared__ bf16_t WkTl[64][72];
  __shared__ bf16_t WvTl[64][72];
  __shared__ bf16_t W1kl[128][72];
  __shared__ bf16_t W1vl[128][72];
  __shared__ float wpxs[64], wpys[64], bpvs[64];
  const int tid = threadIdx.x;
  const int j0 = blockIdx.x * 64;
  // self-fold weights into LDS (coalesced global reads, transpose on LDS write)
  for (int i = tid; i < 4096; i += 256) {
    int n = i & 63, d = i >> 6;      // Wk[i] = Wk[d][n]
    WkTl[n][d] = (bf16_t)Wk[i];
    WvTl[n][d] = (bf16_t)Wv[i];
  }
  for (int i = tid; i < 8192; i += 256) {
    int n = i & 127, c = i >> 7;     // W1[i] = W1[c][n]
    float w = W1[i];
    W1kl[n][c] = (bf16_t)(g_k[c] * w);
    W1vl[n][c] = (bf16_t)(g_v[c] * w);
  }
  if (tid < 64) { wpxs[tid] = W_pos[tid]; wpys[tid] = W_pos[64 + tid]; bpvs[tid] = b_pos[tid]; }
  {
    const int px = tid >> 2, cg = tid & 3;
    const float* rowp = inp + (size_t)(j0 + px) * 64 + cg * 16;
    float v[16];
    *(float4*)&v[0]  = ((const float4*)rowp)[0];
    *(float4*)&v[4]  = ((const float4*)rowp)[1];
    *(float4*)&v[8]  = ((const float4*)rowp)[2];
    *(float4*)&v[12] = ((const float4*)rowp)[3];
    float s = 0.f, s2 = 0.f;
#pragma unroll
    for (int i = 0; i < 16; ++i) { s += v[i]; s2 += v[i] * v[i]; }
    s += __shfl_xor(s, 1, 64); s += __shfl_xor(s, 2, 64);
    s2 += __shfl_xor(s2, 1, 64); s2 += __shfl_xor(s2, 2, 64);
    float m = s * 0.015625f;
    float r = rsqrtf(s2 * 0.015625f - m * m + 1e-5f);
    float g[16], bb[16];
    *(float4*)&g[0]  = ((const float4*)(g_in + cg * 16))[0];
    *(float4*)&g[4]  = ((const float4*)(g_in + cg * 16))[1];
    *(float4*)&g[8]  = ((const float4*)(g_in + cg * 16))[2];
    *(float4*)&g[12] = ((const float4*)(g_in + cg * 16))[3];
    *(float4*)&bb[0]  = ((const float4*)(b_in + cg * 16))[0];
    *(float4*)&bb[4]  = ((const float4*)(b_in + cg * 16))[1];
    *(float4*)&bb[8]  = ((const float4*)(b_in + cg * 16))[2];
    *(float4*)&bb[12] = ((const float4*)(b_in + cg * 16))[3];
#pragma unroll
    for (int e = 0; e < 8; ++e) {
      float x0 = (v[2 * e] - m) * r * g[2 * e] + bb[2 * e];
      float x1 = (v[2 * e + 1] - m) * r * g[2 * e + 1] + bb[2 * e + 1];
      union { unsigned u; bf16_t h[2]; } cv;
      cv.h[0] = (bf16_t)x0; cv.h[1] = (bf16_t)x1;
      *(unsigned*)&xs[px][cg * 16 + 2 * e] = cv.u;
    }
  }
  __syncthreads();
  const int wv = tid >> 6, lane = tid & 63, lq = lane >> 4, ln15 = lane & 15;
  pass_type(xs, t0s, WkTl, W1kl, bk, wpxs, wpys, bpvs, statsK, P0k, j0, wv, lq, ln15);
  __syncthreads();   // t0s reused by V pass
  pass_type(xs, t0s, WvTl, W1vl, bv, wpxs, wpys, bpvs, statsV, P0v, j0, wv, lq, ln15);
  // initial q / w2q / b2q (first 64 blocks; slots_p is batch-broadcast)
  if (blockIdx.x < 64 && tid < 64) {
    int bs = blockIdx.x, d = tid;
    float v = slots_p[(bs & 7) * 64 + d];
    float m = wave_sum(v) * 0.015625f;
    float c = v - m;
    float var = wave_sum(c * c) * 0.015625f;
    float xn = c * rsqrtf(var + 1e-5f) * g_slots[d] + b_slots[d];
    float q = bq[d];
    for (int cc = 0; cc < 64; ++cc) q = fmaf(__shfl(xn, cc, 64), Wq[cc * 64 + d], q);
    float w0 = 0.f, w1 = 0.f;
    for (int cc = 0; cc < 64; ++cc) {
      float qc = __shfl(q, cc, 64);
      w0 = fmaf(W2[d * 64 + cc], qc, w0);
      w1 = fmaf(W2[(64 + d) * 64 + cc], qc, w1);
    }
    w2qg[bs * 128 + d] = w0;
    w2qg[bs * 128 + 64 + d] = w1;
    float p = wave_sum(b2[d] * q);
    if (d == 0) b2qg[bs] = p;
  }
  // folded-constant extras (consumed by k_iter, a later kernel)
  if (blockIdx.x == 508 && tid < 128) {
    int n = tid;
    float wx = 0, wy = 0, wb = 0, u = 0, sk = 0;
    for (int c = 0; c < 64; ++c) {
      float w = W1[c * 128 + n];
      float wf = g_k[c] * w;
      float px = W_pos[c], py = W_pos[64 + c], bp = b_pos[c];
      wx += px * wf; wy += py * wf; wb += bp * wf; sk += wf; u += b_k[c] * w;
    }
    nckA[n] = make_float4(wx, wy, wb, u + b1[n]); nckB[n] = sk;
  }
  if (blockIdx.x == 509 && tid < 128) {
    int n = tid;
    float wx = 0, wy = 0, wb = 0, u = 0, sv = 0;
    for (int c = 0; c < 64; ++c) {
      float w = W1[c * 128 + n];
      float wf = g_v[c] * w;
      float px = W_pos[c], py = W_pos[64 + c], bp = b_pos[c];
      wx += px * wf; wy += py * wf; wb += bp * wf; sv += wf; u += b_v[c] * w;
    }
    ncvA[n] = make_float4(wx, wy, wb, u + b1[n]); ncvB[n] = sv;
  }
  if (blockIdx.x == 510) {
    if (tid < 64) {
      float px = W_pos[tid], py = W_pos[64 + tid], bp = b_pos[tid];
      float s9[9] = {px, py, bp, px * px, py * py, bp * bp, px * py, px * bp, py * bp};
#pragma unroll
      for (int i = 0; i < 9; ++i) {
        float v = wave_sum(s9[i]);
        if (tid == 0) possum[i] = v;
      }
    }
    if (tid < 128) {
      sposS[tid] = fminf(fmaxf(s_pos_p[tid & 15], -1.f), 1.f);
      sscaleS[tid] = fminf(fmaxf(s_scale_p[tid & 15], 0.001f), 2.f);
    }
    for (int i = tid; i < 4096; i += 256) slotsS[i] = slots_p[i & 511];
  }
}

// ============ k_iter: dots(8 slots) -> softmax -> moments -> V-hidden sum ====
// partial outputs per tile (plain stores; no device atomics)
template <int LAST>
__global__ __launch_bounds__(256) void k_iter(
    const bf16_t* __restrict__ P0kg, const bf16_t* __restrict__ P0vg,
    const float* __restrict__ statsK, const float* __restrict__ statsV,
    const float4* __restrict__ nckA, const float* __restrict__ nckB,
    const float4* __restrict__ ncvA, const float* __restrict__ ncvB,
    const float* __restrict__ possum, const float* __restrict__ w2qg,
    const float* __restrict__ b2qg, const float* __restrict__ sposS,
    const float* __restrict__ sscaleS, float* __restrict__ momP,
    float* __restrict__ HsumP, float* __restrict__ outAttn) {
  __shared__ unsigned P0kl[64 * 65];
  __shared__ unsigned P0vl[64 * 65];
  __shared__ float4 nckAl[128];
  __shared__ float nckBl[128];
  __shared__ float w2qTl[128][8];
  __shared__ float4 scalV[64][9];
  __shared__ float attnS[64][10];
  __shared__ float HsumW[4][8][128];
  __shared__ float momAcc[8][5];
  const int tid = threadIdx.x;
  const int tile = blockIdx.x, b = blockIdx.y;
  const int jg0 = b * 4096 + tile * 64;
#pragma unroll
  for (int r = 0; r < 4; ++r) {
    int idx = tid + 256 * r;
    int row = idx >> 4, seg = idx & 15;
    uint4 v = ((const uint4*)P0kg)[(size_t)(jg0 + row) * 16 + seg];
    unsigned* dst = &P0kl[row * 65 + seg * 4];
    dst[0] = v.x; dst[1] = v.y; dst[2] = v.z; dst[3] = v.w;
    if (!LAST) {
      uint4 w = ((const uint4*)P0vg)[(size_t)(jg0 + row) * 16 + seg];
      unsigned* d2 = &P0vl[row * 65 + seg * 4];
      d2[0] = w.x; d2[1] = w.y; d2[2] = w.z; d2[3] = w.w;
    }
  }
  if (tid < 128) { nckAl[tid] = nckA[tid]; nckBl[tid] = nckB[tid]; }
#pragma unroll
  for (int r = 0; r < 4; ++r) {
    int idx = tid + 256 * r;
    int s = idx >> 7, n = idx & 127;
    w2qTl[n][s] = w2qg[(b * 8 + s) * 128 + n];
  }
  if (tid < 40) momAcc[tid / 5][tid % 5] = 0.f;
  float4 ncv0 = {0, 0, 0, 0}, ncv1 = {0, 0, 0, 0};
  float wsv0 = 0.f, wsv1 = 0.f;
  if (!LAST) {
    int l = tid & 63;
    ncv0 = ncvA[l]; ncv1 = ncvA[l + 64];
    wsv0 = ncvB[l]; wsv1 = ncvB[l + 64];
  }
  __syncthreads();

  // ---- phase 1: dots for all 8 slots (k-range split over 4 lanes/pixel) ----
  const int px = tid >> 2, sp = tid & 3;
  const int jimg = tile * 64 + px;
  const float gx = lin_(jimg & 63), gy = lin_(jimg >> 6);
  const float Swx = possum[0], Swy = possum[1], Sbp = possum[2];
  const float Swx2 = possum[3], Swy2 = possum[4], Sbp2 = possum[5];
  const float Swxy = possum[6], Swxb = possum[7], Swyb = possum[8];
  float skA[5], svA[5];
#pragma unroll
  for (int i = 0; i < 5; ++i) {
    skA[i] = statsK[(size_t)(jg0 + px) * 5 + i];
    svA[i] = statsV[(size_t)(jg0 + px) * 5 + i];
  }
  float c1a[8], c2a[8], rKa[8], mrKa[8];
#pragma unroll
  for (int s = 0; s < 8; ++s) {
    int bs = b * 8 + s;
    float spx = sposS[bs * 2], spy = sposS[bs * 2 + 1];
    float rxx = 1.f / (sscaleS[bs * 2] * 5.f);
    float ryy = 1.f / (sscaleS[bs * 2 + 1] * 5.f);
    float c1 = (gx - spx) * rxx, c2 = (gy - spy) * ryy;
    float quad = c1 * c1 * Swx2 + c2 * c2 * Swy2 + Sbp2 +
                 2.f * (c1 * c2 * Swxy + c1 * Swxb + c2 * Swyb);
    float mK = (skA[0] + c1 * Swx + c2 * Swy + Sbp) * 0.015625f;
    float e2K = (skA[1] + 2.f * (c1 * skA[2] + c2 * skA[3] + skA[4]) + quad) * 0.015625f;
    float rK = rsqrtf(e2K - mK * mK + 1e-5f);
    c1a[s] = c1; c2a[s] = c2; rKa[s] = rK; mrKa[s] = mK * rK;
    if (!LAST && (s >> 1) == sp) {
      float mV = (svA[0] + c1 * Swx + c2 * Swy + Sbp) * 0.015625f;
      float e2V = (svA[1] + 2.f * (c1 * svA[2] + c2 * svA[3] + svA[4]) + quad) * 0.015625f;
      float rV = rsqrtf(e2V - mV * mV + 1e-5f);
      scalV[px][s] = make_float4(c1, c2, rV, mV * rV);
    }
  }
  float d8[8] = {0, 0, 0, 0, 0, 0, 0, 0};
#pragma unroll 4
  for (int i = 0; i < 16; ++i) {
    int k = sp * 16 + i;
    unsigned u = P0kl[px * 65 + k];
    float p0 = bflo(u), p1 = bfhi(u);
    float4 A0 = nckAl[2 * k], A1 = nckAl[2 * k + 1];
    float ws0 = nckBl[2 * k], ws1 = nckBl[2 * k + 1];
    float4 q0a = *(const float4*)&w2qTl[2 * k][0];
    float4 q0b = *(const float4*)&w2qTl[2 * k][4];
    float4 q1a = *(const float4*)&w2qTl[2 * k + 1][0];
    float4 q1b = *(const float4*)&w2qTl[2 * k + 1][4];
    float qq0[8] = {q0a.x, q0a.y, q0a.z, q0a.w, q0b.x, q0b.y, q0b.z, q0b.w};
    float qq1[8] = {q1a.x, q1a.y, q1a.z, q1a.w, q1b.x, q1b.y, q1b.z, q1b.w};
    float bm0 = p0 + A0.z, bm1 = p1 + A1.z;
#pragma unroll
    for (int s = 0; s < 8; ++s) {
      float z0 = bm0 + c1a[s] * A0.x + c2a[s] * A0.y;
      float h0 = fmaxf(fmaf(rKa[s], z0, fmaf(-mrKa[s], ws0, A0.w)), 0.f);
      d8[s] = fmaf(h0, qq0[s], d8[s]);
      float z1 = bm1 + c1a[s] * A1.x + c2a[s] * A1.y;
      float h1 = fmaxf(fmaf(rKa[s], z1, fmaf(-mrKa[s], ws1, A1.w)), 0.f);
      d8[s] = fmaf(h1, qq1[s], d8[s]);
    }
  }
#pragma unroll
  for (int s = 0; s < 8; ++s) {
    float v = d8[s];
    v += __shfl_xor(v, 1, 64);
    v += __shfl_xor(v, 2, 64);
    d8[s] = (v + b2qg[b * 8 + s]) * 0.125f;
  }
  float mx = d8[0];
#pragma unroll
  for (int s = 1; s < 8; ++s) mx = fmaxf(mx, d8[s]);
  float tt = 0.f;
  float e8[8];
#pragma unroll
  for (int s = 0; s < 8; ++s) { e8[s] = expf(d8[s] - mx); tt += e8[s]; }
  float inv = 1.f / tt;
#pragma unroll
  for (int s = 0; s < 8; ++s) e8[s] = e8[s] * inv + 1e-8f;
  float wa, wb;
  if (sp == 0) { wa = e8[0]; wb = e8[1]; }
  else if (sp == 1) { wa = e8[2]; wb = e8[3]; }
  else if (sp == 2) { wa = e8[4]; wb = e8[5]; }
  else { wa = e8[6]; wb = e8[7]; }
  *(float2*)&attnS[px][sp * 2] = make_float2(wa, wb);
  if (LAST) {
    outAttn[(size_t)(b * 8 + sp * 2) * 4096 + jimg] = wa;
    outAttn[(size_t)(b * 8 + sp * 2 + 1) * 4096 + jimg] = wb;
  }
  {
    float mm[10] = {wa, wa * gx, wa * gy, wa * gx * gx, wa * gy * gy,
                    wb, wb * gx, wb * gy, wb * gx * gx, wb * gy * gy};
#pragma unroll
    for (int i = 0; i < 10; ++i) {
      float v = mm[i];
      v += __shfl_xor(v, 4, 64); v += __shfl_xor(v, 8, 64);
      v += __shfl_xor(v, 16, 64); v += __shfl_xor(v, 32, 64);
      mm[i] = v;
    }
    if ((tid & 63) < 4) {
#pragma unroll
      for (int i = 0; i < 5; ++i) {
        atomicAdd(&momAcc[sp * 2][i], mm[i]);
        atomicAdd(&momAcc[sp * 2 + 1][i], mm[5 + i]);
      }
    }
  }
  __syncthreads();

  // ---- phase 2: Hsum partial = attn * relu(V hidden), plain store ----------
  if (!LAST) {
    const int w = tid >> 6, l = tid & 63;
    float hacc[8][2];
#pragma unroll
    for (int s = 0; s < 8; ++s) { hacc[s][0] = 0.f; hacc[s][1] = 0.f; }
    const unsigned short* P16 = (const unsigned short*)P0vl;
#pragma unroll 2
    for (int i = 0; i < 16; ++i) {
      int j = w * 16 + i;
      float pv0 = __uint_as_float((unsigned)P16[j * 130 + l] << 16);
      float pv1 = __uint_as_float((unsigned)P16[j * 130 + 64 + l] << 16);
      float bm0 = pv0 + ncv0.z, bm1 = pv1 + ncv1.z;
#pragma unroll
      for (int s = 0; s < 8; ++s) {
        float4 sc = scalV[j][s];
        float aw = attnS[j][s];
        float z0 = bm0 + sc.x * ncv0.x + sc.y * ncv0.y;
        float h0 = fmaxf(fmaf(sc.z, z0, fmaf(-sc.w, wsv0, ncv0.w)), 0.f);
        hacc[s][0] = fmaf(aw, h0, hacc[s][0]);
        float z1 = bm1 + sc.x * ncv1.x + sc.y * ncv1.y;
        float h1 = fmaxf(fmaf(sc.z, z1, fmaf(-sc.w, wsv1, ncv1.w)), 0.f);
        hacc[s][1] = fmaf(aw, h1, hacc[s][1]);
      }
    }
#pragma unroll
    for (int s = 0; s < 8; ++s) {
      HsumW[w][s][l] = hacc[s][0];
      HsumW[w][s][l + 64] = hacc[s][1];
    }
    __syncthreads();
#pragma unroll
    for (int r = 0; r < 4; ++r) {
      int i = tid + 256 * r;
      int s = i >> 7, n = i & 127;
      float v = HsumW[0][s][n] + HsumW[1][s][n] + HsumW[2][s][n] + HsumW[3][s][n];
      HsumP[((size_t)(b * 8 + s) * 64 + tile) * 128 + n] = v;
    }
  }
  if (tid < 40)
    momP[((size_t)(b * 8 + tid / 5) * 64 + tile) * 5 + tid % 5] =
        momAcc[tid / 5][tid % 5];
}

// ============ k_fin: reduce partials -> sp/ss, GRU + FFN, next-iter q ========
__global__ __launch_bounds__(192) void k_fin(
    const float* __restrict__ momP, const float* __restrict__ HsumP,
    const float* __restrict__ W2, const float* __restrict__ b2,
    const float* __restrict__ W_ih, const float* __restrict__ b_ih,
    const float* __restrict__ W_hh, const float* __restrict__ b_hh,
    const float* __restrict__ g_pre, const float* __restrict__ b_pre,
    const float* __restrict__ Wf1, const float* __restrict__ bf1,
    const float* __restrict__ Wf2, const float* __restrict__ bf2,
    const float* __restrict__ g_slots, const float* __restrict__ b_slots,
    const float* __restrict__ Wq, const float* __restrict__ bq,
    float* __restrict__ slotsS, float* __restrict__ sposS, float* __restrict__ sscaleS,
    float* __restrict__ w2qg, float* __restrict__ b2qg,
    float* __restrict__ outSlots, float* __restrict__ outSpos,
    float* __restrict__ outSscale, int last) {
  const int bs = blockIdx.x;
  const int t = threadIdx.x;
  __shared__ float hsum_s[128], upd[64], sprev[64], xg[192], hg[192];
  __shared__ float snew[64], xpre[64], hf[128], sfin[64], xn[64], qsh[64];
  __shared__ float mom_s[5];
  // wave 0: moments reduce over 64 tiles
  if (t < 64) {
    const float* mp = momP + ((size_t)bs * 64 + t) * 5;
    float m0 = mp[0], m1 = mp[1], m2 = mp[2], m3 = mp[3], m4 = mp[4];
    m0 = wave_sum(m0); m1 = wave_sum(m1); m2 = wave_sum(m2);
    m3 = wave_sum(m3); m4 = wave_sum(m4);
    if (t == 0) { mom_s[0] = m0; mom_s[1] = m1; mom_s[2] = m2; mom_s[3] = m3; mom_s[4] = m4; }
    if (!last) sprev[t] = slotsS[bs * 64 + t];
  }
  // waves 1-2: Hsum reduce over 64 tiles
  if (!last && t >= 64) {
    int n = t - 64;
    const float* hp = HsumP + (size_t)bs * 8192 + n;
    float a = 0.f;
#pragma unroll 8
    for (int tile = 0; tile < 64; ++tile) a += hp[tile * 128];
    hsum_s[n] = a;
  }
  __syncthreads();
  const float M0 = mom_s[0];
  const float M1x = mom_s[1], M1y = mom_s[2];
  const float M2x = mom_s[3], M2y = mom_s[4];
  const float invM0 = 1.f / M0;
  const float spx = M1x * invM0, spy = M1y * invM0;
  const float M0a = M0 + 4096.f * 1e-8f;
  const float G2 = 1408.6772487f * 1e-8f;
  const float vx = (M2x + G2 - 2.f * spx * M1x + spx * spx * M0a) / M0a;
  const float vy = (M2y + G2 - 2.f * spy * M1y + spy * spy * M0a) / M0a;
  float ssx = sqrtf(fmaxf(vx, 0.f)), ssy = sqrtf(fmaxf(vy, 0.f));
  ssx = fminf(fmaxf(ssx, 0.001f), 2.f);
  ssy = fminf(fmaxf(ssy, 0.001f), 2.f);
  if (t == 0) {
    sposS[bs * 2 + 0] = spx; sposS[bs * 2 + 1] = spy;
    sscaleS[bs * 2 + 0] = ssx; sscaleS[bs * 2 + 1] = ssy;
    if (last) {
      outSpos[bs * 2 + 0] = spx; outSpos[bs * 2 + 1] = spy;
      outSscale[bs * 2 + 0] = ssx; outSscale[bs * 2 + 1] = ssy;
    }
  }
  if (last) {
    if (t < 64) outSlots[bs * 64 + t] = slotsS[bs * 64 + t];
    return;
  }
  if (t < 64) {
    float a = 0.f;
#pragma unroll
    for (int k = 0; k < 128; ++k) a += hsum_s[k] * W2[k * 64 + t];
    upd[t] = a * invM0 + b2[t];
  }
  __syncthreads();
  {
    float a = b_ih[t], h = b_hh[t];
#pragma unroll
    for (int d = 0; d < 64; ++d) {
      a += upd[d] * W_ih[d * 192 + t];
      h += sprev[d] * W_hh[d * 192 + t];
    }
    xg[t] = a; hg[t] = h;
  }
  __syncthreads();
  if (t < 64) {
    float r = 1.f / (1.f + expf(-(xg[t] + hg[t])));
    float z = 1.f / (1.f + expf(-(xg[64 + t] + hg[64 + t])));
    float n = tanhf(xg[128 + t] + r * hg[128 + t]);
    snew[t] = (1.f - z) * n + z * sprev[t];
  }
  __syncthreads();
  if (t < 64) {
    float v = snew[t];
    float m = wave_sum(v) * 0.015625f;
    float c = v - m;
    float var = wave_sum(c * c) * 0.015625f;
    xpre[t] = c * rsqrtf(var + 1e-5f) * g_pre[t] + b_pre[t];
  }
  __syncthreads();
  if (t < 128) {
    float a = bf1[t];
#pragma unroll
    for (int d = 0; d < 64; ++d) a += xpre[d] * Wf1[d * 128 + t];
    hf[t] = fmaxf(a, 0.f);
  }
  __syncthreads();
  if (t < 64) {
    float a = bf2[t];
#pragma unroll
    for (int k = 0; k < 128; ++k) a += hf[k] * Wf2[k * 64 + t];
    float nv = snew[t] + a;
    slotsS[bs * 64 + t] = nv;
    sfin[t] = nv;
  }
  __syncthreads();
  if (t < 64) {
    float v = sfin[t];
    float m = wave_sum(v) * 0.015625f;
    float c = v - m;
    float var = wave_sum(c * c) * 0.015625f;
    xn[t] = c * rsqrtf(var + 1e-5f) * g_slots[t] + b_slots[t];
  }
  __syncthreads();
  if (t < 64) {
    float a = bq[t];
#pragma unroll
    for (int d = 0; d < 64; ++d) a += xn[d] * Wq[d * 64 + t];
    qsh[t] = a;
  }
  __syncthreads();
  if (t < 128) {
    float a = 0.f;
#pragma unroll
    for (int d = 0; d < 64; ++d) a += W2[t * 64 + d] * qsh[d];
    w2qg[bs * 128 + t] = a;
  }
  if (t < 64) {
    float p = wave_sum(b2[t] * qsh[t]);
    if (t == 0) b2qg[bs] = p;
  }
}

extern "C" void kernel_launch(void* const* d_in, const int* in_sizes, int n_in,
                              void* d_out, int out_size, void* d_ws, size_t ws_size,
                              hipStream_t stream) {
  (void)in_sizes; (void)n_in; (void)out_size; (void)ws_size;
  const float* const* in = (const float* const*)d_in;
  float* ws = (float*)d_ws;
  bf16_t* P0k   = (bf16_t*)(ws + 0);        // 2,097,152 f32 slots
  bf16_t* P0v   = (bf16_t*)(ws + 2097152);
  float* statsK = ws + 4194304;             // 163,840
  float* statsV = ws + 4358144;             // 163,840
  float* w2qg   = ws + 4521984;             // 8192
  float* b2qg   = ws + 4530176;             // 64
  float* slotsS = ws + 4530240;             // 4096
  float* sposS  = ws + 4534336;             // 128
  float* sscaleS= ws + 4534464;             // 128
  float4* nckA  = (float4*)(ws + 4555392);  // 512 f32 slots
  float* nckB   = ws + 4555904;             // 128
  float4* ncvA  = (float4*)(ws + 4556032);  // 512
  float* ncvB   = ws + 4556544;             // 128
  float* possum = ws + 4556672;             // 9
  float* HsumP  = ws + 4560896;             // 64*64*128 = 524288
  float* momP   = ws + 5085184;             // 64*64*5   = 20480

  float* out = (float*)d_out;
  float* outSlots  = out;
  float* outSpos   = out + 4096;
  float* outSscale = out + 4224;
  float* outAttn   = out + 4352;

  k_pre<<<512, 256, 0, stream>>>(
      in[0], in[12], in[13], in[9], in[11], in[8], in[10], in[20], in[16], in[18],
      in[4], in[5], P0k, P0v, statsK, statsV,
      in[1], in[14], in[15], in[6], in[7], in[22], in[23], w2qg, b2qg,
      in[17], in[19], in[21], in[2], in[3],
      nckA, nckB, ncvA, ncvB, possum, sposS, sscaleS, slotsS);
  for (int i = 0; i < 4; ++i) {
    int last = (i == 3) ? 1 : 0;
    if (!last) {
      k_iter<0><<<dim3(64, 8), 256, 0, stream>>>(
          P0k, P0v, statsK, statsV, nckA, nckB, ncvA, ncvB, possum,
          w2qg, b2qg, sposS, sscaleS, momP, HsumP, outAttn);
    } else {
      k_iter<1><<<dim3(64, 8), 256, 0, stream>>>(
          P0k, P0v, statsK, statsV, nckA, nckB, ncvA, ncvB, possum,
          w2qg, b2qg, sposS, sscaleS, momP, HsumP, outAttn);
    }
    k_fin<<<64, 192, 0, stream>>>(momP, HsumP, in[22], in[23], in[24], in[25],
                                  in[26], in[27], in[28], in[29], in[30], in[31],
                                  in[32], in[33], in[14], in[15], in[6], in[7],
                                  slotsS, sposS, sscaleS, w2qg, b2qg,
                                  outSlots, outSpos, outSscale, last);
  }
}

// Round 4
// 266.423 us; speedup vs baseline: 3.3065x; 1.0776x over previous
//
#include <hip/hip_runtime.h>
#include <math.h>

typedef __bf16 bf16_t;
typedef __bf16 bfrag __attribute__((ext_vector_type(8)));
typedef float ffrag __attribute__((ext_vector_type(4)));

__device__ __forceinline__ float wave_sum(float v) {
#pragma unroll
  for (int m = 32; m >= 1; m >>= 1) v += __shfl_xor(v, m, 64);
  return v;
}
__device__ __forceinline__ float lin_(int i) { return -1.f + (2.f * (float)i) / 63.f; }
__device__ __forceinline__ float bflo(unsigned u) { return __uint_as_float(u << 16); }
__device__ __forceinline__ float bfhi(unsigned u) { return __uint_as_float(u & 0xFFFF0000u); }

// ============ k_pre: LN(inp) -> K/V hidden P0 + LN stats; self-folds weights =
__device__ __forceinline__ void pass_type(
    const bf16_t xs[][72], bf16_t t0s[][72],
    const bf16_t WTl[][72], const bf16_t W1l[][72],
    const float* __restrict__ bias, const float* wpxs, const float* wpys,
    const float* bpvs, float* __restrict__ statsG, bf16_t* __restrict__ P0G,
    int j0, int wv, int lq, int ln15) {
  ffrag C[4] = {{0,0,0,0},{0,0,0,0},{0,0,0,0},{0,0,0,0}};
#pragma unroll
  for (int ks = 0; ks < 2; ++ks) {
    bfrag a = *(const bfrag*)&xs[wv * 16 + ln15][ks * 32 + lq * 8];
#pragma unroll
    for (int nt = 0; nt < 4; ++nt) {
      bfrag bb = *(const bfrag*)&WTl[nt * 16 + ln15][ks * 32 + lq * 8];
      C[nt] = __builtin_amdgcn_mfma_f32_16x16x32_bf16(a, bb, C[nt], 0, 0, 0);
    }
  }
  float kv[4][4];
  float st[5][4];
#pragma unroll
  for (int i = 0; i < 5; ++i)
#pragma unroll
    for (int rg = 0; rg < 4; ++rg) st[i][rg] = 0.f;
#pragma unroll
  for (int nt = 0; nt < 4; ++nt) {
    int n = nt * 16 + ln15;
    float bn = bias[n], pxw = wpxs[n], pyw = wpys[n], bpw = bpvs[n];
#pragma unroll
    for (int rg = 0; rg < 4; ++rg) {
      float v = C[nt][rg] + bn;
      kv[nt][rg] = v;
      st[0][rg] += v; st[1][rg] += v * v; st[2][rg] += v * pxw;
      st[3][rg] += v * pyw; st[4][rg] += v * bpw;
    }
  }
#pragma unroll
  for (int i = 0; i < 5; ++i)
#pragma unroll
    for (int rg = 0; rg < 4; ++rg) {
      float v = st[i][rg];
      v += __shfl_xor(v, 1, 64); v += __shfl_xor(v, 2, 64);
      v += __shfl_xor(v, 4, 64); v += __shfl_xor(v, 8, 64);
      st[i][rg] = v;
    }
  if (ln15 == 0) {
#pragma unroll
    for (int rg = 0; rg < 4; ++rg) {
      int j = j0 + wv * 16 + lq * 4 + rg;
#pragma unroll
      for (int i = 0; i < 5; ++i) statsG[j * 5 + i] = st[i][rg];
    }
  }
#pragma unroll
  for (int nt = 0; nt < 4; ++nt)
#pragma unroll
    for (int rg = 0; rg < 4; ++rg)
      t0s[wv * 16 + lq * 4 + rg][nt * 16 + ln15] = (bf16_t)kv[nt][rg];
  ffrag D[8] = {{0,0,0,0},{0,0,0,0},{0,0,0,0},{0,0,0,0},
                {0,0,0,0},{0,0,0,0},{0,0,0,0},{0,0,0,0}};
#pragma unroll
  for (int ks = 0; ks < 2; ++ks) {
    bfrag a = *(const bfrag*)&t0s[wv * 16 + ln15][ks * 32 + lq * 8];
#pragma unroll
    for (int nt = 0; nt < 8; ++nt) {
      bfrag bb = *(const bfrag*)&W1l[nt * 16 + ln15][ks * 32 + lq * 8];
      D[nt] = __builtin_amdgcn_mfma_f32_16x16x32_bf16(a, bb, D[nt], 0, 0, 0);
    }
  }
#pragma unroll
  for (int nt = 0; nt < 8; ++nt)
#pragma unroll
    for (int rg = 0; rg < 4; ++rg)
      P0G[(size_t)(j0 + wv * 16 + lq * 4 + rg) * 128 + nt * 16 + ln15] =
          (bf16_t)D[nt][rg];
}

__global__ __launch_bounds__(256) void k_pre(
    const float* __restrict__ inp, const float* __restrict__ g_in,
    const float* __restrict__ b_in, const float* __restrict__ bk,
    const float* __restrict__ bv, const float* __restrict__ Wk,
    const float* __restrict__ Wv, const float* __restrict__ W1,
    const float* __restrict__ g_k, const float* __restrict__ g_v,
    const float* __restrict__ W_pos, const float* __restrict__ b_pos,
    bf16_t* __restrict__ P0k, bf16_t* __restrict__ P0v,
    float* __restrict__ statsK, float* __restrict__ statsV,
    const float* __restrict__ slots_p, const float* __restrict__ g_slots,
    const float* __restrict__ b_slots, const float* __restrict__ Wq,
    const float* __restrict__ bq, const float* __restrict__ W2,
    const float* __restrict__ b2, float* __restrict__ w2qg,
    float* __restrict__ b2qg,
    const float* __restrict__ b_k, const float* __restrict__ b_v,
    const float* __restrict__ b1, const float* __restrict__ s_pos_p,
    const float* __restrict__ s_scale_p,
    float4* __restrict__ nckA, float* __restrict__ nckB,
    float4* __restrict__ ncvA, float* __restrict__ ncvB,
    float* __restrict__ possum, float* __restrict__ sposS,
    float* __restrict__ sscaleS, float* __restrict__ slotsS) {
  __shared__ bf16_t xs[64][72];
  __shared__ bf16_t t0s[64][72];
  __shared__ bf16_t WkTl[64][72];
  __shared__ bf16_t WvTl[64][72];
  __shared__ bf16_t W1kl[128][72];
  __shared__ bf16_t W1vl[128][72];
  __shared__ float wpxs[64], wpys[64], bpvs[64];
  const int tid = threadIdx.x;
  const int j0 = blockIdx.x * 64;
  for (int i = tid; i < 4096; i += 256) {
    int n = i & 63, d = i >> 6;
    WkTl[n][d] = (bf16_t)Wk[i];
    WvTl[n][d] = (bf16_t)Wv[i];
  }
  for (int i = tid; i < 8192; i += 256) {
    int n = i & 127, c = i >> 7;
    float w = W1[i];
    W1kl[n][c] = (bf16_t)(g_k[c] * w);
    W1vl[n][c] = (bf16_t)(g_v[c] * w);
  }
  if (tid < 64) { wpxs[tid] = W_pos[tid]; wpys[tid] = W_pos[64 + tid]; bpvs[tid] = b_pos[tid]; }
  {
    const int px = tid >> 2, cg = tid & 3;
    const float* rowp = inp + (size_t)(j0 + px) * 64 + cg * 16;
    float v[16];
    *(float4*)&v[0]  = ((const float4*)rowp)[0];
    *(float4*)&v[4]  = ((const float4*)rowp)[1];
    *(float4*)&v[8]  = ((const float4*)rowp)[2];
    *(float4*)&v[12] = ((const float4*)rowp)[3];
    float s = 0.f, s2 = 0.f;
#pragma unroll
    for (int i = 0; i < 16; ++i) { s += v[i]; s2 += v[i] * v[i]; }
    s += __shfl_xor(s, 1, 64); s += __shfl_xor(s, 2, 64);
    s2 += __shfl_xor(s2, 1, 64); s2 += __shfl_xor(s2, 2, 64);
    float m = s * 0.015625f;
    float r = rsqrtf(s2 * 0.015625f - m * m + 1e-5f);
    float g[16], bb[16];
    *(float4*)&g[0]  = ((const float4*)(g_in + cg * 16))[0];
    *(float4*)&g[4]  = ((const float4*)(g_in + cg * 16))[1];
    *(float4*)&g[8]  = ((const float4*)(g_in + cg * 16))[2];
    *(float4*)&g[12] = ((const float4*)(g_in + cg * 16))[3];
    *(float4*)&bb[0]  = ((const float4*)(b_in + cg * 16))[0];
    *(float4*)&bb[4]  = ((const float4*)(b_in + cg * 16))[1];
    *(float4*)&bb[8]  = ((const float4*)(b_in + cg * 16))[2];
    *(float4*)&bb[12] = ((const float4*)(b_in + cg * 16))[3];
#pragma unroll
    for (int e = 0; e < 8; ++e) {
      float x0 = (v[2 * e] - m) * r * g[2 * e] + bb[2 * e];
      float x1 = (v[2 * e + 1] - m) * r * g[2 * e + 1] + bb[2 * e + 1];
      union { unsigned u; bf16_t h[2]; } cv;
      cv.h[0] = (bf16_t)x0; cv.h[1] = (bf16_t)x1;
      *(unsigned*)&xs[px][cg * 16 + 2 * e] = cv.u;
    }
  }
  __syncthreads();
  const int wv = tid >> 6, lane = tid & 63, lq = lane >> 4, ln15 = lane & 15;
  pass_type(xs, t0s, WkTl, W1kl, bk, wpxs, wpys, bpvs, statsK, P0k, j0, wv, lq, ln15);
  __syncthreads();
  pass_type(xs, t0s, WvTl, W1vl, bv, wpxs, wpys, bpvs, statsV, P0v, j0, wv, lq, ln15);
  if (blockIdx.x < 64 && tid < 64) {
    int bs = blockIdx.x, d = tid;
    float v = slots_p[(bs & 7) * 64 + d];
    float m = wave_sum(v) * 0.015625f;
    float c = v - m;
    float var = wave_sum(c * c) * 0.015625f;
    float xn = c * rsqrtf(var + 1e-5f) * g_slots[d] + b_slots[d];
    float q = bq[d];
    for (int cc = 0; cc < 64; ++cc) q = fmaf(__shfl(xn, cc, 64), Wq[cc * 64 + d], q);
    float w0 = 0.f, w1 = 0.f;
    for (int cc = 0; cc < 64; ++cc) {
      float qc = __shfl(q, cc, 64);
      w0 = fmaf(W2[d * 64 + cc], qc, w0);
      w1 = fmaf(W2[(64 + d) * 64 + cc], qc, w1);
    }
    w2qg[bs * 128 + d] = w0;
    w2qg[bs * 128 + 64 + d] = w1;
    float p = wave_sum(b2[d] * q);
    if (d == 0) b2qg[bs] = p;
  }
  if (blockIdx.x == 508 && tid < 128) {
    int n = tid;
    float wx = 0, wy = 0, wb = 0, u = 0, sk = 0;
    for (int c = 0; c < 64; ++c) {
      float w = W1[c * 128 + n];
      float wf = g_k[c] * w;
      float px = W_pos[c], py = W_pos[64 + c], bp = b_pos[c];
      wx += px * wf; wy += py * wf; wb += bp * wf; sk += wf; u += b_k[c] * w;
    }
    nckA[n] = make_float4(wx, wy, wb, u + b1[n]); nckB[n] = sk;
  }
  if (blockIdx.x == 509 && tid < 128) {
    int n = tid;
    float wx = 0, wy = 0, wb = 0, u = 0, sv = 0;
    for (int c = 0; c < 64; ++c) {
      float w = W1[c * 128 + n];
      float wf = g_v[c] * w;
      float px = W_pos[c], py = W_pos[64 + c], bp = b_pos[c];
      wx += px * wf; wy += py * wf; wb += bp * wf; sv += wf; u += b_v[c] * w;
    }
    ncvA[n] = make_float4(wx, wy, wb, u + b1[n]); ncvB[n] = sv;
  }
  if (blockIdx.x == 510) {
    if (tid < 64) {
      float px = W_pos[tid], py = W_pos[64 + tid], bp = b_pos[tid];
      float s9[9] = {px, py, bp, px * px, py * py, bp * bp, px * py, px * bp, py * bp};
#pragma unroll
      for (int i = 0; i < 9; ++i) {
        float v = wave_sum(s9[i]);
        if (tid == 0) possum[i] = v;
      }
    }
    if (tid < 128) {
      sposS[tid] = fminf(fmaxf(s_pos_p[tid & 15], -1.f), 1.f);
      sscaleS[tid] = fminf(fmaxf(s_scale_p[tid & 15], 0.001f), 2.f);
    }
    for (int i = tid; i < 4096; i += 256) slotsS[i] = slots_p[i & 511];
  }
}

// ============ k_iter: 1024 blocks x 32 pixels; occupancy-first ===============
// phase 1: 8-way k-split dots; phase 2: wave-slot-pair V accumulation.
// ncqT row n (16 floats, rotated by 4*(n>>4 & 3)): [A.xyzw | qq0..7 | ws | pad3]
template <int LAST>
__global__ __launch_bounds__(256, 4) void k_iter(
    const bf16_t* __restrict__ P0kg, const bf16_t* __restrict__ P0vg,
    const float* __restrict__ statsK, const float* __restrict__ statsV,
    const float4* __restrict__ nckA, const float* __restrict__ nckB,
    const float4* __restrict__ ncvA, const float* __restrict__ ncvB,
    const float* __restrict__ possum, const float* __restrict__ w2qg,
    const float* __restrict__ b2qg, const float* __restrict__ sposS,
    const float* __restrict__ sscaleS, float* __restrict__ momP,
    float* __restrict__ HsumP, float* __restrict__ outAttn) {
  __shared__ unsigned P0vl[32 * 65];
  __shared__ float ncqT[128 * 16];
  __shared__ float4 scalV[32][9];
  __shared__ float attnS[32][10];
  __shared__ float momAcc[8][5];
  const int tid = threadIdx.x;
  const int tile = blockIdx.x, b = blockIdx.y;
  const int jg0 = b * 4096 + tile * 32;
  const int px = tid >> 3, sp = tid & 7;
  // register-stage K row segment (no LDS round-trip; zero reuse)
  uint4 pk0 = ((const uint4*)P0kg)[(size_t)(jg0 + px) * 16 + sp * 2 + 0];
  uint4 pk1 = ((const uint4*)P0kg)[(size_t)(jg0 + px) * 16 + sp * 2 + 1];
  float skA[5], svA[5];
#pragma unroll
  for (int i = 0; i < 5; ++i) {
    skA[i] = statsK[(size_t)(jg0 + px) * 5 + i];
    if (!LAST) svA[i] = statsV[(size_t)(jg0 + px) * 5 + i];
  }
  // stage V tile (reused 4x in phase 2)
  if (!LAST) {
#pragma unroll
    for (int r = 0; r < 2; ++r) {
      int idx = tid + 256 * r;
      int row = idx >> 4, seg = idx & 15;
      uint4 w = ((const uint4*)P0vg)[(size_t)(jg0 + row) * 16 + seg];
      unsigned* d2 = &P0vl[row * 65 + seg * 4];
      d2[0] = w.x; d2[1] = w.y; d2[2] = w.z; d2[3] = w.w;
    }
  }
  // stage fused per-n table with float4-aligned rotation (kills 4-way aliasing)
  {
    int n = tid & 127, g = tid >> 7, r4 = ((n >> 4) & 3) * 4;
    float* row = &ncqT[n * 16];
    if (g == 0) {
      float4 A = nckA[n];
      row[(0 + r4) & 15] = A.x; row[(1 + r4) & 15] = A.y;
      row[(2 + r4) & 15] = A.z; row[(3 + r4) & 15] = A.w;
#pragma unroll
      for (int s = 0; s < 4; ++s) row[(4 + s + r4) & 15] = w2qg[(b * 8 + s) * 128 + n];
    } else {
#pragma unroll
      for (int s = 4; s < 8; ++s) row[(4 + s + r4) & 15] = w2qg[(b * 8 + s) * 128 + n];
      row[(12 + r4) & 15] = nckB[n];
    }
  }
  if (tid < 40) momAcc[tid / 5][tid % 5] = 0.f;
  __syncthreads();

  // ---- phase 1: dots for all 8 slots (8-way k-split per pixel) -------------
  const int jimg = tile * 32 + px;
  const float gx = lin_(jimg & 63), gy = lin_(jimg >> 6);
  const float Swx = possum[0], Swy = possum[1], Sbp = possum[2];
  const float Swx2 = possum[3], Swy2 = possum[4], Sbp2 = possum[5];
  const float Swxy = possum[6], Swxb = possum[7], Swyb = possum[8];
  float c1a[8], c2a[8], rKa[8], mrKa[8];
#pragma unroll
  for (int s = 0; s < 8; ++s) {
    int bs = b * 8 + s;
    float spx = sposS[bs * 2], spy = sposS[bs * 2 + 1];
    float rxx = 1.f / (sscaleS[bs * 2] * 5.f);
    float ryy = 1.f / (sscaleS[bs * 2 + 1] * 5.f);
    float c1 = (gx - spx) * rxx, c2 = (gy - spy) * ryy;
    float quad = c1 * c1 * Swx2 + c2 * c2 * Swy2 + Sbp2 +
                 2.f * (c1 * c2 * Swxy + c1 * Swxb + c2 * Swyb);
    float mK = (skA[0] + c1 * Swx + c2 * Swy + Sbp) * 0.015625f;
    float e2K = (skA[1] + 2.f * (c1 * skA[2] + c2 * skA[3] + skA[4]) + quad) * 0.015625f;
    float rK = rsqrtf(e2K - mK * mK + 1e-5f);
    c1a[s] = c1; c2a[s] = c2; rKa[s] = rK; mrKa[s] = mK * rK;
    if (!LAST && s == sp) {
      float mV = (svA[0] + c1 * Swx + c2 * Swy + Sbp) * 0.015625f;
      float e2V = (svA[1] + 2.f * (c1 * svA[2] + c2 * svA[3] + svA[4]) + quad) * 0.015625f;
      float rV = rsqrtf(e2V - mV * mV + 1e-5f);
      scalV[px][s] = make_float4(c1, c2, rV, mV * rV);
    }
  }
  const unsigned uu[8] = {pk0.x, pk0.y, pk0.z, pk0.w, pk1.x, pk1.y, pk1.z, pk1.w};
  const int r4 = (sp & 3) * 4;
  float d8[8] = {0, 0, 0, 0, 0, 0, 0, 0};
#pragma unroll
  for (int i = 0; i < 8; ++i) {
    int n0 = 16 * sp + 2 * i;
    const float* R0 = &ncqT[n0 * 16];
    const float* R1 = R0 + 16;
    float4 A0 = *(const float4*)&R0[r4];
    float4 q0a = *(const float4*)&R0[(r4 + 4) & 15];
    float4 q0b = *(const float4*)&R0[(r4 + 8) & 15];
    float ws0 = R0[(r4 + 12) & 15];
    float4 A1 = *(const float4*)&R1[r4];
    float4 q1a = *(const float4*)&R1[(r4 + 4) & 15];
    float4 q1b = *(const float4*)&R1[(r4 + 8) & 15];
    float ws1 = R1[(r4 + 12) & 15];
    float qq0[8] = {q0a.x, q0a.y, q0a.z, q0a.w, q0b.x, q0b.y, q0b.z, q0b.w};
    float qq1[8] = {q1a.x, q1a.y, q1a.z, q1a.w, q1b.x, q1b.y, q1b.z, q1b.w};
    float p0 = bflo(uu[i]), p1 = bfhi(uu[i]);
    float bm0 = p0 + A0.z, bm1 = p1 + A1.z;
#pragma unroll
    for (int s = 0; s < 8; ++s) {
      float z0 = bm0 + c1a[s] * A0.x + c2a[s] * A0.y;
      float h0 = fmaxf(fmaf(rKa[s], z0, fmaf(-mrKa[s], ws0, A0.w)), 0.f);
      d8[s] = fmaf(h0, qq0[s], d8[s]);
      float z1 = bm1 + c1a[s] * A1.x + c2a[s] * A1.y;
      float h1 = fmaxf(fmaf(rKa[s], z1, fmaf(-mrKa[s], ws1, A1.w)), 0.f);
      d8[s] = fmaf(h1, qq1[s], d8[s]);
    }
  }
#pragma unroll
  for (int s = 0; s < 8; ++s) {
    float v = d8[s];
    v += __shfl_xor(v, 1, 64);
    v += __shfl_xor(v, 2, 64);
    v += __shfl_xor(v, 4, 64);
    d8[s] = (v + b2qg[b * 8 + s]) * 0.125f;
  }
  float mx = d8[0];
#pragma unroll
  for (int s = 1; s < 8; ++s) mx = fmaxf(mx, d8[s]);
  float tt = 0.f;
  float e8[8];
#pragma unroll
  for (int s = 0; s < 8; ++s) { e8[s] = expf(d8[s] - mx); tt += e8[s]; }
  float inv = 1.f / tt;
#pragma unroll
  for (int s = 0; s < 8; ++s) e8[s] = e8[s] * inv + 1e-8f;
  attnS[px][sp] = e8[sp];
  if (LAST) outAttn[(size_t)(b * 8 + sp) * 4096 + jimg] = e8[sp];
  {
    float w = e8[sp];
    float mm[5] = {w, w * gx, w * gy, w * gx * gx, w * gy * gy};
#pragma unroll
    for (int i = 0; i < 5; ++i) {
      float v = mm[i];
      v += __shfl_xor(v, 8, 64); v += __shfl_xor(v, 16, 64);
      v += __shfl_xor(v, 32, 64);
      mm[i] = v;
    }
    if ((tid & 63) < 8) {
#pragma unroll
      for (int i = 0; i < 5; ++i) atomicAdd(&momAcc[sp][i], mm[i]);
    }
  }
  __syncthreads();
  if (tid < 40)
    momP[((size_t)(b * 8 + tid / 5) * 128 + tile) * 5 + tid % 5] =
        momAcc[tid / 5][tid % 5];

  // ---- phase 2: wave w -> slots 2w,2w+1; thread -> cols 2l,2l+1 -------------
  if (!LAST) {
    const int w = tid >> 6, l = tid & 63;
    const int s0 = 2 * w, s1 = 2 * w + 1;
    float4 cv0 = ncvA[2 * l], cv1 = ncvA[2 * l + 1];
    float wv0 = ncvB[2 * l], wv1 = ncvB[2 * l + 1];
    float h00 = 0.f, h01 = 0.f, h10 = 0.f, h11 = 0.f;
#pragma unroll 4
    for (int j = 0; j < 32; ++j) {
      unsigned u = P0vl[j * 65 + l];
      float pv0 = bflo(u), pv1 = bfhi(u);
      float bm0 = pv0 + cv0.z, bm1 = pv1 + cv1.z;
      float4 sa = scalV[j][s0]; float aw = attnS[j][s0];
      float z0 = bm0 + sa.x * cv0.x + sa.y * cv0.y;
      h00 = fmaf(aw, fmaxf(fmaf(sa.z, z0, fmaf(-sa.w, wv0, cv0.w)), 0.f), h00);
      float z1 = bm1 + sa.x * cv1.x + sa.y * cv1.y;
      h01 = fmaf(aw, fmaxf(fmaf(sa.z, z1, fmaf(-sa.w, wv1, cv1.w)), 0.f), h01);
      float4 sb = scalV[j][s1]; float ab = attnS[j][s1];
      float z2 = bm0 + sb.x * cv0.x + sb.y * cv0.y;
      h10 = fmaf(ab, fmaxf(fmaf(sb.z, z2, fmaf(-sb.w, wv0, cv0.w)), 0.f), h10);
      float z3 = bm1 + sb.x * cv1.x + sb.y * cv1.y;
      h11 = fmaf(ab, fmaxf(fmaf(sb.z, z3, fmaf(-sb.w, wv1, cv1.w)), 0.f), h11);
    }
    *(float2*)&HsumP[((size_t)(b * 8 + s0) * 128 + tile) * 128 + 2 * l] =
        make_float2(h00, h01);
    *(float2*)&HsumP[((size_t)(b * 8 + s1) * 128 + tile) * 128 + 2 * l] =
        make_float2(h10, h11);
  }
}

// ============ k_fin: reduce partials -> sp/ss, GRU + FFN, next-iter q ========
__global__ __launch_bounds__(192) void k_fin(
    const float* __restrict__ momP, const float* __restrict__ HsumP,
    const float* __restrict__ W2, const float* __restrict__ b2,
    const float* __restrict__ W_ih, const float* __restrict__ b_ih,
    const float* __restrict__ W_hh, const float* __restrict__ b_hh,
    const float* __restrict__ g_pre, const float* __restrict__ b_pre,
    const float* __restrict__ Wf1, const float* __restrict__ bf1,
    const float* __restrict__ Wf2, const float* __restrict__ bf2,
    const float* __restrict__ g_slots, const float* __restrict__ b_slots,
    const float* __restrict__ Wq, const float* __restrict__ bq,
    float* __restrict__ slotsS, float* __restrict__ sposS, float* __restrict__ sscaleS,
    float* __restrict__ w2qg, float* __restrict__ b2qg,
    float* __restrict__ outSlots, float* __restrict__ outSpos,
    float* __restrict__ outSscale, int last) {
  const int bs = blockIdx.x;
  const int t = threadIdx.x;
  __shared__ float hsum_s[128], upd[64], sprev[64], xg[192], hg[192];
  __shared__ float snew[64], xpre[64], hf[128], sfin[64], xn[64], qsh[64];
  __shared__ float mom_s[5];
  if (t < 64) {
    const float* mp = momP + ((size_t)bs * 128 + t) * 5;
    float m0 = mp[0] + mp[320], m1 = mp[1] + mp[321], m2 = mp[2] + mp[322];
    float m3 = mp[3] + mp[323], m4 = mp[4] + mp[324];
    m0 = wave_sum(m0); m1 = wave_sum(m1); m2 = wave_sum(m2);
    m3 = wave_sum(m3); m4 = wave_sum(m4);
    if (t == 0) { mom_s[0] = m0; mom_s[1] = m1; mom_s[2] = m2; mom_s[3] = m3; mom_s[4] = m4; }
    if (!last) sprev[t] = slotsS[bs * 64 + t];
  }
  if (!last && t >= 64) {
    int n = t - 64;
    const float* hp = HsumP + (size_t)bs * 16384 + n;
    float a = 0.f;
#pragma unroll 8
    for (int tile = 0; tile < 128; ++tile) a += hp[tile * 128];
    hsum_s[n] = a;
  }
  __syncthreads();
  const float M0 = mom_s[0];
  const float M1x = mom_s[1], M1y = mom_s[2];
  const float M2x = mom_s[3], M2y = mom_s[4];
  const float invM0 = 1.f / M0;
  const float spx = M1x * invM0, spy = M1y * invM0;
  const float M0a = M0 + 4096.f * 1e-8f;
  const float G2 = 1408.6772487f * 1e-8f;
  const float vx = (M2x + G2 - 2.f * spx * M1x + spx * spx * M0a) / M0a;
  const float vy = (M2y + G2 - 2.f * spy * M1y + spy * spy * M0a) / M0a;
  float ssx = sqrtf(fmaxf(vx, 0.f)), ssy = sqrtf(fmaxf(vy, 0.f));
  ssx = fminf(fmaxf(ssx, 0.001f), 2.f);
  ssy = fminf(fmaxf(ssy, 0.001f), 2.f);
  if (t == 0) {
    sposS[bs * 2 + 0] = spx; sposS[bs * 2 + 1] = spy;
    sscaleS[bs * 2 + 0] = ssx; sscaleS[bs * 2 + 1] = ssy;
    if (last) {
      outSpos[bs * 2 + 0] = spx; outSpos[bs * 2 + 1] = spy;
      outSscale[bs * 2 + 0] = ssx; outSscale[bs * 2 + 1] = ssy;
    }
  }
  if (last) {
    if (t < 64) outSlots[bs * 64 + t] = slotsS[bs * 64 + t];
    return;
  }
  if (t < 64) {
    float a = 0.f;
#pragma unroll
    for (int k = 0; k < 128; ++k) a += hsum_s[k] * W2[k * 64 + t];
    upd[t] = a * invM0 + b2[t];
  }
  __syncthreads();
  {
    float a = b_ih[t], h = b_hh[t];
#pragma unroll
    for (int d = 0; d < 64; ++d) {
      a += upd[d] * W_ih[d * 192 + t];
      h += sprev[d] * W_hh[d * 192 + t];
    }
    xg[t] = a; hg[t] = h;
  }
  __syncthreads();
  if (t < 64) {
    float r = 1.f / (1.f + expf(-(xg[t] + hg[t])));
    float z = 1.f / (1.f + expf(-(xg[64 + t] + hg[64 + t])));
    float n = tanhf(xg[128 + t] + r * hg[128 + t]);
    snew[t] = (1.f - z) * n + z * sprev[t];
  }
  __syncthreads();
  if (t < 64) {
    float v = snew[t];
    float m = wave_sum(v) * 0.015625f;
    float c = v - m;
    float var = wave_sum(c * c) * 0.015625f;
    xpre[t] = c * rsqrtf(var + 1e-5f) * g_pre[t] + b_pre[t];
  }
  __syncthreads();
  if (t < 128) {
    float a = bf1[t];
#pragma unroll
    for (int d = 0; d < 64; ++d) a += xpre[d] * Wf1[d * 128 + t];
    hf[t] = fmaxf(a, 0.f);
  }
  __syncthreads();
  if (t < 64) {
    float a = bf2[t];
#pragma unroll
    for (int k = 0; k < 128; ++k) a += hf[k] * Wf2[k * 64 + t];
    float nv = snew[t] + a;
    slotsS[bs * 64 + t] = nv;
    sfin[t] = nv;
  }
  __syncthreads();
  if (t < 64) {
    float v = sfin[t];
    float m = wave_sum(v) * 0.015625f;
    float c = v - m;
    float var = wave_sum(c * c) * 0.015625f;
    xn[t] = c * rsqrtf(var + 1e-5f) * g_slots[t] + b_slots[t];
  }
  __syncthreads();
  if (t < 64) {
    float a = bq[t];
#pragma unroll
    for (int d = 0; d < 64; ++d) a += xn[d] * Wq[d * 64 + t];
    qsh[t] = a;
  }
  __syncthreads();
  if (t < 128) {
    float a = 0.f;
#pragma unroll
    for (int d = 0; d < 64; ++d) a += W2[t * 64 + d] * qsh[d];
    w2qg[bs * 128 + t] = a;
  }
  if (t < 64) {
    float p = wave_sum(b2[t] * qsh[t]);
    if (t == 0) b2qg[bs] = p;
  }
}

extern "C" void kernel_launch(void* const* d_in, const int* in_sizes, int n_in,
                              void* d_out, int out_size, void* d_ws, size_t ws_size,
                              hipStream_t stream) {
  (void)in_sizes; (void)n_in; (void)out_size; (void)ws_size;
  const float* const* in = (const float* const*)d_in;
  float* ws = (float*)d_ws;
  bf16_t* P0k   = (bf16_t*)(ws + 0);        // 2,097,152 f32 slots
  bf16_t* P0v   = (bf16_t*)(ws + 2097152);
  float* statsK = ws + 4194304;             // 163,840
  float* statsV = ws + 4358144;             // 163,840
  float* w2qg   = ws + 4521984;             // 8192
  float* b2qg   = ws + 4530176;             // 64
  float* slotsS = ws + 4530240;             // 4096
  float* sposS  = ws + 4534336;             // 128
  float* sscaleS= ws + 4534464;             // 128
  float4* nckA  = (float4*)(ws + 4555392);  // 512 f32 slots
  float* nckB   = ws + 4555904;             // 128
  float4* ncvA  = (float4*)(ws + 4556032);  // 512
  float* ncvB   = ws + 4556544;             // 128
  float* possum = ws + 4556672;             // 9
  float* HsumP  = ws + 4560896;             // 64*128*128 = 1,048,576
  float* momP   = ws + 5609472;             // 64*128*5   = 40,960

  float* out = (float*)d_out;
  float* outSlots  = out;
  float* outSpos   = out + 4096;
  float* outSscale = out + 4224;
  float* outAttn   = out + 4352;

  k_pre<<<512, 256, 0, stream>>>(
      in[0], in[12], in[13], in[9], in[11], in[8], in[10], in[20], in[16], in[18],
      in[4], in[5], P0k, P0v, statsK, statsV,
      in[1], in[14], in[15], in[6], in[7], in[22], in[23], w2qg, b2qg,
      in[17], in[19], in[21], in[2], in[3],
      nckA, nckB, ncvA, ncvB, possum, sposS, sscaleS, slotsS);
  for (int i = 0; i < 4; ++i) {
    int last = (i == 3) ? 1 : 0;
    if (!last) {
      k_iter<0><<<dim3(128, 8), 256, 0, stream>>>(
          P0k, P0v, statsK, statsV, nckA, nckB, ncvA, ncvB, possum,
          w2qg, b2qg, sposS, sscaleS, momP, HsumP, outAttn);
    } else {
      k_iter<1><<<dim3(128, 8), 256, 0, stream>>>(
          P0k, P0v, statsK, statsV, nckA, nckB, ncvA, ncvB, possum,
          w2qg, b2qg, sposS, sscaleS, momP, HsumP, outAttn);
    }
    k_fin<<<64, 192, 0, stream>>>(momP, HsumP, in[22], in[23], in[24], in[25],
                                  in[26], in[27], in[28], in[29], in[30], in[31],
                                  in[32], in[33], in[14], in[15], in[6], in[7],
                                  slotsS, sposS, sscaleS, w2qg, b2qg,
                                  outSlots, outSpos, outSscale, last);
  }
}